// Round 3
// baseline (306.967 us; speedup 1.0000x reference)
//
#include <hip/hip_runtime.h>

// BinCat: out[b,i,:] = cats[idx(b,i),:],  idx = 0xFFFFF ^ pack(x[b,i,:]).
// B=4096, I=16, L=20, D=64. Pure random gather from a 256 MB table.
//
// Round-2 finding: measured 305 us/iter decomposes as ~162 us harness
// re-poison fill (1.07 GB @ 6.6 TB/s, 82% HBM peak — top-5 dispatches are
// all fillBufferAligned) + kernel. This version strips the kernel to the
// bone: no LDS, no barriers, register-only index fold via shfl_xor.

#define BATCH 4096
#define I_DIM 16
#define LENGTH 20
#define DIM 64

#define ROWS (BATCH * I_DIM)          // 65536
#define ROWS_PER_BLOCK 64
#define THREADS 256
#define PASSES ((ROWS_PER_BLOCK * (DIM / 4)) / THREADS)   // 4

// Native vectors: accepted by __builtin_nontemporal_{load,store},
// lower to global_{load,store}_dwordx4.
typedef __attribute__((ext_vector_type(4))) float f32x4;
typedef __attribute__((ext_vector_type(4))) int   i32x4;

__global__ __launch_bounds__(THREADS) void bincat_gather(
    const int* __restrict__ x,      // (ROWS, LENGTH) int32 in {0,1}
    const float* __restrict__ cats, // (2^20, DIM) fp32
    float* __restrict__ out)        // (ROWS, DIM) fp32
{
    const int t   = threadIdx.x;
    const int sub = t >> 4;   // row-slot within pass (0..15); 16 consecutive
    const int pos = t & 15;   // lanes (one shuffle group) serve one row
    const int row0 = blockIdx.x * ROWS_PER_BLOCK;

    // ---- Index fold, fully in registers ----------------------------------
    // Row = 20 ints = 5 int4 (80 B, 16 B-aligned). Lanes pos<5 each load one
    // int4 and fold its 4 bits; OR-reduce across the 16-lane group.
    int idx[PASSES];
    #pragma unroll
    for (int p = 0; p < PASSES; ++p) {
        const int row = row0 + p * 16 + sub;
        int partial = 0;
        if (pos < 5) {
            i32x4 b = __builtin_nontemporal_load(
                (const i32x4*)(x + (size_t)row * LENGTH) + pos);
            const int hi = 19 - 4 * pos;          // weight of bit 4*pos
            partial = (b.x << hi) | (b.y << (hi - 1)) |
                      (b.z << (hi - 2)) | (b.w << (hi - 3));
        }
        #pragma unroll
        for (int m = 1; m < 16; m <<= 1)
            partial |= __shfl_xor(partial, m, 16);
        idx[p] = 0xFFFFF ^ partial;               // bits are {0,1}: 1-b == b^1
    }

    // ---- Gather: 4 independent float4 loads in flight per thread --------
    f32x4 v[PASSES];
    #pragma unroll
    for (int p = 0; p < PASSES; ++p) {
        v[p] = *((const f32x4*)(cats + (size_t)idx[p] * DIM) + pos);
    }

    // ---- Store: write-once stream, non-temporal -------------------------
    #pragma unroll
    for (int p = 0; p < PASSES; ++p) {
        f32x4* dst = (f32x4*)(out + (size_t)(row0 + p * 16 + sub) * DIM) + pos;
        __builtin_nontemporal_store(v[p], dst);
    }
}

extern "C" void kernel_launch(void* const* d_in, const int* in_sizes, int n_in,
                              void* d_out, int out_size, void* d_ws, size_t ws_size,
                              hipStream_t stream) {
    const int* x = (const int*)d_in[0];        // (4096,16,20) int32
    const float* cats = (const float*)d_in[1]; // (2^20, 64) fp32
    float* out = (float*)d_out;                // (4096,16,64) fp32

    dim3 grid(ROWS / ROWS_PER_BLOCK); // 1024 blocks
    dim3 block(THREADS);
    bincat_gather<<<grid, block, 0, stream>>>(x, cats, out);
}